// Round 11
// baseline (461.723 us; speedup 1.0000x reference)
//
#include <hip/hip_runtime.h>

// ---------------------------------------------------------------------------
// GCN round 11: single change vs r10 — agg gathers 4 edges per wave-load
// (uint4, one wave/node, 4 slots x 16 lanes x 16B = 1KB per load instr),
// with the r4 inactive-lane-shfl bug fixed (tail shfl runs on ALL lanes).
// ---------------------------------------------------------------------------

using frag  = __attribute__((ext_vector_type(8))) short;   // 8 bf16
using f32x4 = __attribute__((ext_vector_type(4))) float;

static __device__ __forceinline__ short f2bf(float f) {
    union { float f; unsigned u; } x; x.f = f;
    unsigned r = x.u + 0x7FFF + ((x.u >> 16) & 1);         // RNE
    return (short)(r >> 16);
}
static __device__ __forceinline__ float bflo(unsigned u) {
    union { unsigned u; float f; } x; x.u = u << 16; return x.f;
}
static __device__ __forceinline__ float bfhi(unsigned u) {
    union { unsigned u; float f; } x; x.u = u & 0xffff0000u; return x.f;
}
static __device__ __forceinline__ unsigned pack2(float a, float b) {
    return (unsigned)(unsigned short)f2bf(a) | ((unsigned)(unsigned short)f2bf(b) << 16);
}

// ---- graph build: padded histograms + slotted CSR (r6/r7-validated) --------
__global__ void build_kernel(const int* __restrict__ src, const int* __restrict__ dst,
                             int* __restrict__ cnt_out, int* __restrict__ cnt_in,
                             int* __restrict__ slot, int E) {
    int i = blockIdx.x * blockDim.x + threadIdx.x;
    if (i < E) {
        int s = src[i], d = dst[i];
        atomicAdd(&cnt_out[s << 4], 1);
        int pos = atomicAdd(&cnt_in[d << 4], 1);
        if (pos < 64) slot[((size_t)d << 6) + pos] = s;     // MAXDEG=64
    }
}

__global__ void norm_kernel(const int* __restrict__ cnt, float* __restrict__ norm, int n) {
    int i = blockIdx.x * blockDim.x + threadIdx.x;
    if (i < n) norm[i] = rsqrtf((float)max(cnt[i << 4], 1));
}

// ---- weight packing --------------------------------------------------------

__global__ void pack128_kernel(const float* __restrict__ W, const float* __restrict__ L,
                               short* __restrict__ Bt) {
    int gid = blockIdx.x * blockDim.x + threadIdx.x;
    if (gid >= 256 * 128) return;
    int n = gid >> 7, k = gid & 127;
    float v = (n < 128) ? W[k * 128 + n] : L[k * 128 + (n - 128)];
    Bt[gid] = f2bf(v);
}

__global__ void pack_final_kernel(const float* __restrict__ W2, const float* __restrict__ L2,
                                  short* __restrict__ Bt) {
    int gid = blockIdx.x * blockDim.x + threadIdx.x;
    if (gid >= 48 * 256) return;
    int n = gid >> 8, k = gid & 255;
    float v = 0.0f;
    if (n < 40) v = (k < 128) ? W2[k * 40 + n] : L2[(k - 128) * 40 + n];
    Bt[gid] = f2bf(v);
}

// ---- GEMM (layers 1,2): [P | R] = A @ [W | L], P scaled (r5-validated) -----
static __device__ __forceinline__ frag load_frag_f32(const float* p) {
    float4 f0 = *reinterpret_cast<const float4*>(p);
    float4 f1 = *reinterpret_cast<const float4*>(p + 4);
    union { frag f; unsigned u[4]; } t;
    t.u[0] = pack2(f0.x, f0.y); t.u[1] = pack2(f0.z, f0.w);
    t.u[2] = pack2(f1.x, f1.y); t.u[3] = pack2(f1.z, f1.w);
    return t.f;
}

template<bool AF32>
__global__ __launch_bounds__(256) void gemm128(
    const void* __restrict__ A,        // M x 128 (fp32 if AF32 else bf16)
    const short* __restrict__ Bt,      // 256 x 128 bf16
    const float* __restrict__ norm_src,
    short* __restrict__ P,
    short* __restrict__ R,
    int M)
{
    const int lane = threadIdx.x & 63;
    const int wid  = threadIdx.x >> 6;
    const int row0 = (blockIdx.x * 4 + wid) * 32;
    if (row0 >= M) return;
    const int lrow = lane & 15;
    const int lk8  = (lane >> 4) << 3;
    const int g4   = (lane >> 4) << 2;

    const int r0 = row0 + lrow, r1 = row0 + 16 + lrow;
    const int a0r = min(r0, M - 1), a1r = min(r1, M - 1);

    frag a0[4], a1[4];
#pragma unroll
    for (int ks = 0; ks < 4; ++ks) {
        if (AF32) {
            const float* Af = (const float*)A;
            a0[ks] = load_frag_f32(Af + (size_t)a0r * 128 + lk8 + ks * 32);
            a1[ks] = load_frag_f32(Af + (size_t)a1r * 128 + lk8 + ks * 32);
        } else {
            const short* Ab = (const short*)A;
            a0[ks] = *reinterpret_cast<const frag*>(Ab + (size_t)a0r * 128 + lk8 + ks * 32);
            a1[ks] = *reinterpret_cast<const frag*>(Ab + (size_t)a1r * 128 + lk8 + ks * 32);
        }
    }
    const float ns0 = norm_src[a0r], ns1 = norm_src[a1r];

#pragma unroll
    for (int nt = 0; nt < 16; ++nt) {
        frag b[4];
#pragma unroll
        for (int ks = 0; ks < 4; ++ks)
            b[ks] = *reinterpret_cast<const frag*>(Bt + (size_t)(nt * 16 + lrow) * 128 + lk8 + ks * 32);
        f32x4 acc0 = {0.f, 0.f, 0.f, 0.f};
        f32x4 acc1 = {0.f, 0.f, 0.f, 0.f};
#pragma unroll
        for (int ks = 0; ks < 4; ++ks) {
            acc0 = __builtin_amdgcn_mfma_f32_16x16x32_bf16(b[ks], a0[ks], acc0, 0, 0, 0);
            acc1 = __builtin_amdgcn_mfma_f32_16x16x32_bf16(b[ks], a1[ks], acc1, 0, 0, 0);
        }
        const int cb = nt * 16 + g4;
        if (cb < 128) {
            uint2 p0, p1;
            p0.x = pack2(acc0[0] * ns0, acc0[1] * ns0);
            p0.y = pack2(acc0[2] * ns0, acc0[3] * ns0);
            p1.x = pack2(acc1[0] * ns1, acc1[1] * ns1);
            p1.y = pack2(acc1[2] * ns1, acc1[3] * ns1);
            if (r0 < M) *reinterpret_cast<uint2*>(P + (size_t)r0 * 128 + cb) = p0;
            if (r1 < M) *reinterpret_cast<uint2*>(P + (size_t)r1 * 128 + cb) = p1;
        } else {
            const int oc = cb - 128;
            uint2 p0, p1;
            p0.x = pack2(acc0[0], acc0[1]); p0.y = pack2(acc0[2], acc0[3]);
            p1.x = pack2(acc1[0], acc1[1]); p1.y = pack2(acc1[2], acc1[3]);
            if (r0 < M) *reinterpret_cast<uint2*>(R + (size_t)r0 * 128 + oc) = p0;
            if (r1 < M) *reinterpret_cast<uint2*>(R + (size_t)r1 * 128 + oc) = p1;
        }
    }
}

// ---- final GEMM: out = [m2 | h2] @ Bt3^T + bias  (r6-validated) ------------
__global__ __launch_bounds__(256) void gemm_final(
    const short* __restrict__ M2,
    const short* __restrict__ H2,
    const short* __restrict__ Bt,      // 48 x 256
    const float* __restrict__ bias,
    float* __restrict__ OUT,
    int M)
{
    const int lane = threadIdx.x & 63;
    const int wid  = threadIdx.x >> 6;
    const int row0 = (blockIdx.x * 4 + wid) * 32;
    if (row0 >= M) return;
    const int lrow = lane & 15;
    const int lk8  = (lane >> 4) << 3;
    const int g4   = (lane >> 4) << 2;

    const int r0 = row0 + lrow, r1 = row0 + 16 + lrow;
    const int a0r = min(r0, M - 1), a1r = min(r1, M - 1);

    frag a0[8], a1[8];
#pragma unroll
    for (int ks = 0; ks < 4; ++ks) {
        a0[ks]     = *reinterpret_cast<const frag*>(M2 + (size_t)a0r * 128 + lk8 + ks * 32);
        a1[ks]     = *reinterpret_cast<const frag*>(M2 + (size_t)a1r * 128 + lk8 + ks * 32);
        a0[ks + 4] = *reinterpret_cast<const frag*>(H2 + (size_t)a0r * 128 + lk8 + ks * 32);
        a1[ks + 4] = *reinterpret_cast<const frag*>(H2 + (size_t)a1r * 128 + lk8 + ks * 32);
    }

#pragma unroll
    for (int nt = 0; nt < 3; ++nt) {
        frag b[8];
#pragma unroll
        for (int ks = 0; ks < 8; ++ks)
            b[ks] = *reinterpret_cast<const frag*>(Bt + (size_t)(nt * 16 + lrow) * 256 + lk8 + ks * 32);
        f32x4 acc0 = {0.f, 0.f, 0.f, 0.f};
        f32x4 acc1 = {0.f, 0.f, 0.f, 0.f};
#pragma unroll
        for (int ks = 0; ks < 8; ++ks) {
            acc0 = __builtin_amdgcn_mfma_f32_16x16x32_bf16(b[ks], a0[ks], acc0, 0, 0, 0);
            acc1 = __builtin_amdgcn_mfma_f32_16x16x32_bf16(b[ks], a1[ks], acc1, 0, 0, 0);
        }
        const int cb = nt * 16 + g4;
        if (cb + 3 < 40) {
            float4 bv = *reinterpret_cast<const float4*>(&bias[cb]);
            if (r0 < M) {
                float4 o = make_float4(acc0[0] + bv.x, acc0[1] + bv.y, acc0[2] + bv.z, acc0[3] + bv.w);
                *reinterpret_cast<float4*>(&OUT[(size_t)r0 * 40 + cb]) = o;
            }
            if (r1 < M) {
                float4 o = make_float4(acc1[0] + bv.x, acc1[1] + bv.y, acc1[2] + bv.z, acc1[3] + bv.w);
                *reinterpret_cast<float4*>(&OUT[(size_t)r1 * 40 + cb]) = o;
            }
        }
    }
}

// ---- aggregation: one wave per node, 4 edges per wave-load (uint4) ---------
// sub = lane>>4 is the edge slot, q = lane&15 the 16B chunk within the row.
// Tail shfl executes on ALL lanes (r4's inactive-source bug fixed); only the
// load/accumulate is predicated. Cross-slot reduce via shfl_xor(16,32).
// MODE 0: H += nd * sum P[s]           (bf16 in-place over residual)
// MODE 2: H  = nd * sum ns[s] * P[s]   (bf16 pure write)
template<int MODE>
__global__ __launch_bounds__(256) void agg_kernel(
    const uint4* __restrict__ P,       // N x 16 uint4 (= N x 128 bf16)
    const int* __restrict__ cnt_in,    // padded x16
    const int* __restrict__ slot,      // N x 64
    const float* __restrict__ norm_src,
    uint4* __restrict__ H,             // N x 16 uint4
    int N)
{
    const int node = blockIdx.x * 4 + (threadIdx.x >> 6);
    if (node >= N) return;
    const int lane = threadIdx.x & 63;
    const int sub  = lane >> 4;
    const int q    = lane & 15;

    const int cnt = cnt_in[node << 4];
    const int c   = min(cnt, 64);
    const size_t sbase = (size_t)node << 6;
    const int cv = (lane < c) ? slot[sbase + lane] : 0;

    float a[8];
#pragma unroll
    for (int i = 0; i < 8; ++i) a[i] = 0.0f;

    int t = 0;
    for (; t + 4 <= c; t += 4) {
        int s = __shfl(cv, t + sub);
        uint4 u = P[(size_t)s * 16 + q];
        float f = (MODE == 2) ? norm_src[s] : 1.0f;
        a[0] += f * bflo(u.x); a[1] += f * bfhi(u.x);
        a[2] += f * bflo(u.y); a[3] += f * bfhi(u.y);
        a[4] += f * bflo(u.z); a[5] += f * bfhi(u.z);
        a[6] += f * bflo(u.w); a[7] += f * bfhi(u.w);
    }
    const int rem = c - t;
    if (rem > 0) {
        int s = __shfl(cv, t + (sub < rem ? sub : 0));   // all lanes execute
        if (sub < rem) {
            uint4 u = P[(size_t)s * 16 + q];
            float f = (MODE == 2) ? norm_src[s] : 1.0f;
            a[0] += f * bflo(u.x); a[1] += f * bfhi(u.x);
            a[2] += f * bflo(u.y); a[3] += f * bfhi(u.y);
            a[4] += f * bflo(u.z); a[5] += f * bfhi(u.z);
            a[6] += f * bflo(u.w); a[7] += f * bfhi(u.w);
        }
    }
#pragma unroll
    for (int i = 0; i < 8; ++i) {
        a[i] += __shfl_xor(a[i], 16);
        a[i] += __shfl_xor(a[i], 32);
    }
    if (sub == 0) {
        const float nd = rsqrtf((float)max(cnt, 1));
        const size_t o = (size_t)node * 16 + q;
        uint4 w;
        if (MODE == 2) {
            w.x = pack2(nd * a[0], nd * a[1]);
            w.y = pack2(nd * a[2], nd * a[3]);
            w.z = pack2(nd * a[4], nd * a[5]);
            w.w = pack2(nd * a[6], nd * a[7]);
        } else {
            uint4 r = H[o];
            w.x = pack2(bflo(r.x) + nd * a[0], bfhi(r.x) + nd * a[1]);
            w.y = pack2(bflo(r.y) + nd * a[2], bfhi(r.y) + nd * a[3]);
            w.z = pack2(bflo(r.z) + nd * a[4], bfhi(r.z) + nd * a[5]);
            w.w = pack2(bflo(r.w) + nd * a[6], bfhi(r.w) + nd * a[7]);
        }
        H[o] = w;
    }
}

// ---------------------------------------------------------------------------

extern "C" void kernel_launch(void* const* d_in, const int* in_sizes, int n_in,
                              void* d_out, int out_size, void* d_ws, size_t ws_size,
                              hipStream_t stream) {
    const float* feat = (const float*)d_in[0];
    const int*   src  = (const int*)d_in[1];
    const int*   dst  = (const int*)d_in[2];
    const float* W0   = (const float*)d_in[3];
    const float* W1   = (const float*)d_in[4];
    const float* W2   = (const float*)d_in[5];
    const float* b2   = (const float*)d_in[6];
    const float* L0   = (const float*)d_in[7];
    const float* L1   = (const float*)d_in[8];
    const float* L2   = (const float*)d_in[9];
    float* out = (float*)d_out;

    const int E = in_sizes[1];
    const int N = in_sizes[0] / 128;

    // ---- workspace layout ----
    float* fws      = (float*)d_ws;
    float* norm_src = fws;                        // N
    short* sws      = (short*)(fws + N);
    short* bufP     = sws;                        // N*128 (P scratch)
    short* bufA     = bufP + (size_t)N * 128;     // N*128 (R1 -> h1, later m2)
    short* bufB     = bufA + (size_t)N * 128;     // N*128 (h2)
    short* Bt1      = bufB + (size_t)N * 128;     // 256*128
    short* Bt2      = Bt1 + 256 * 128;
    short* Bt3      = Bt2 + 256 * 128;            // 48*256
    int*   iws      = (int*)(Bt3 + 48 * 256);
    int*   cnt_out  = iws;                        // N*16 (padded)
    int*   cnt_in   = iws + (size_t)N * 16;       // N*16 (padded, slot cursor)
    int*   slot     = iws + 2 * (size_t)N * 16;   // N*64

    const int gblocks = (N + 127) / 128;
    const int ablocks = (N + 3) / 4;              // one node per wave

    // ---- graph build ----
    hipMemsetAsync(cnt_out, 0, 2 * (size_t)N * 16 * sizeof(int), stream);
    build_kernel<<<(E + 255) / 256, 256, 0, stream>>>(src, dst, cnt_out, cnt_in, slot, E);
    norm_kernel<<<(N + 255) / 256, 256, 0, stream>>>(cnt_out, norm_src, N);

    pack128_kernel<<<(256 * 128 + 255) / 256, 256, 0, stream>>>(W0, L0, Bt1);
    pack128_kernel<<<(256 * 128 + 255) / 256, 256, 0, stream>>>(W1, L1, Bt2);
    pack_final_kernel<<<(48 * 256 + 255) / 256, 256, 0, stream>>>(W2, L2, Bt3);

    // layer 1: h1 = agg(P1) + R1                                   -> bufA
    gemm128<true><<<gblocks, 256, 0, stream>>>(feat, Bt1, norm_src, bufP, bufA, N);
    agg_kernel<0><<<ablocks, 256, 0, stream>>>((const uint4*)bufP, cnt_in, slot,
        nullptr, (uint4*)bufA, N);

    // layer 2: h2 = agg(P2) + R2                                   -> bufB
    gemm128<false><<<gblocks, 256, 0, stream>>>(bufA, Bt2, norm_src, bufP, bufB, N);
    agg_kernel<0><<<ablocks, 256, 0, stream>>>((const uint4*)bufP, cnt_in, slot,
        nullptr, (uint4*)bufB, N);

    // layer 3: m2 = nd * sum ns[s]*h2[s] -> bufA; out = [m2|h2]@Bt3 + b2
    agg_kernel<2><<<ablocks, 256, 0, stream>>>((const uint4*)bufB, cnt_in, slot,
        norm_src, (uint4*)bufA, N);
    gemm_final<<<gblocks, 256, 0, stream>>>(bufA, bufB, Bt3, b2, out, N);
}

// Round 13
// 461.236 us; speedup vs baseline: 1.0011x; 1.0011x over previous
//
#include <hip/hip_runtime.h>
#include <hip/hip_bf16.h>

// ---------------------------------------------------------------------------
// GCN round 13: r12 retry with the correct API — scalar __float2bfloat16
// (HW RNE; compiler fuses pairs into v_cvt_pk_bf16_f32 per m240: scalar casts
// beat hand-written asm). Compact counters. Everything else identical to r11.
// ---------------------------------------------------------------------------

using frag  = __attribute__((ext_vector_type(8))) short;   // 8 bf16
using f32x4 = __attribute__((ext_vector_type(4))) float;

static __device__ __forceinline__ short f2bf(float f) {
    __hip_bfloat16 h = __float2bfloat16(f);                // HW RNE conversion
    union { __hip_bfloat16 h; short s; } c; c.h = h;
    return c.s;
}
static __device__ __forceinline__ unsigned pack2(float a, float b) {
    return (unsigned)(unsigned short)f2bf(a) | ((unsigned)(unsigned short)f2bf(b) << 16);
}
static __device__ __forceinline__ float bflo(unsigned u) {
    union { unsigned u; float f; } x; x.u = u << 16; return x.f;
}
static __device__ __forceinline__ float bfhi(unsigned u) {
    union { unsigned u; float f; } x; x.u = u & 0xffff0000u; return x.f;
}

// ---- graph build: compact histograms + slotted CSR -------------------------
__global__ void build_kernel(const int* __restrict__ src, const int* __restrict__ dst,
                             int* __restrict__ cnt_out, int* __restrict__ cnt_in,
                             int* __restrict__ slot, int E) {
    int i = blockIdx.x * blockDim.x + threadIdx.x;
    if (i < E) {
        int s = src[i], d = dst[i];
        atomicAdd(&cnt_out[s], 1);
        int pos = atomicAdd(&cnt_in[d], 1);
        if (pos < 64) slot[((size_t)d << 6) + pos] = s;     // MAXDEG=64
    }
}

__global__ void norm_kernel(const int* __restrict__ cnt, float* __restrict__ norm, int n) {
    int i = blockIdx.x * blockDim.x + threadIdx.x;
    if (i < n) norm[i] = rsqrtf((float)max(cnt[i], 1));
}

// ---- weight packing --------------------------------------------------------

__global__ void pack128_kernel(const float* __restrict__ W, const float* __restrict__ L,
                               short* __restrict__ Bt) {
    int gid = blockIdx.x * blockDim.x + threadIdx.x;
    if (gid >= 256 * 128) return;
    int n = gid >> 7, k = gid & 127;
    float v = (n < 128) ? W[k * 128 + n] : L[k * 128 + (n - 128)];
    Bt[gid] = f2bf(v);
}

__global__ void pack_final_kernel(const float* __restrict__ W2, const float* __restrict__ L2,
                                  short* __restrict__ Bt) {
    int gid = blockIdx.x * blockDim.x + threadIdx.x;
    if (gid >= 48 * 256) return;
    int n = gid >> 8, k = gid & 255;
    float v = 0.0f;
    if (n < 40) v = (k < 128) ? W2[k * 40 + n] : L2[(k - 128) * 40 + n];
    Bt[gid] = f2bf(v);
}

// ---- GEMM (layers 1,2): [P | R] = A @ [W | L], P scaled (r5-validated) -----
static __device__ __forceinline__ frag load_frag_f32(const float* p) {
    float4 f0 = *reinterpret_cast<const float4*>(p);
    float4 f1 = *reinterpret_cast<const float4*>(p + 4);
    union { frag f; unsigned u[4]; } t;
    t.u[0] = pack2(f0.x, f0.y); t.u[1] = pack2(f0.z, f0.w);
    t.u[2] = pack2(f1.x, f1.y); t.u[3] = pack2(f1.z, f1.w);
    return t.f;
}

template<bool AF32>
__global__ __launch_bounds__(256) void gemm128(
    const void* __restrict__ A,        // M x 128 (fp32 if AF32 else bf16)
    const short* __restrict__ Bt,      // 256 x 128 bf16
    const float* __restrict__ norm_src,
    short* __restrict__ P,
    short* __restrict__ R,
    int M)
{
    const int lane = threadIdx.x & 63;
    const int wid  = threadIdx.x >> 6;
    const int row0 = (blockIdx.x * 4 + wid) * 32;
    if (row0 >= M) return;
    const int lrow = lane & 15;
    const int lk8  = (lane >> 4) << 3;
    const int g4   = (lane >> 4) << 2;

    const int r0 = row0 + lrow, r1 = row0 + 16 + lrow;
    const int a0r = min(r0, M - 1), a1r = min(r1, M - 1);

    frag a0[4], a1[4];
#pragma unroll
    for (int ks = 0; ks < 4; ++ks) {
        if (AF32) {
            const float* Af = (const float*)A;
            a0[ks] = load_frag_f32(Af + (size_t)a0r * 128 + lk8 + ks * 32);
            a1[ks] = load_frag_f32(Af + (size_t)a1r * 128 + lk8 + ks * 32);
        } else {
            const short* Ab = (const short*)A;
            a0[ks] = *reinterpret_cast<const frag*>(Ab + (size_t)a0r * 128 + lk8 + ks * 32);
            a1[ks] = *reinterpret_cast<const frag*>(Ab + (size_t)a1r * 128 + lk8 + ks * 32);
        }
    }
    const float ns0 = norm_src[a0r], ns1 = norm_src[a1r];

#pragma unroll
    for (int nt = 0; nt < 16; ++nt) {
        frag b[4];
#pragma unroll
        for (int ks = 0; ks < 4; ++ks)
            b[ks] = *reinterpret_cast<const frag*>(Bt + (size_t)(nt * 16 + lrow) * 128 + lk8 + ks * 32);
        f32x4 acc0 = {0.f, 0.f, 0.f, 0.f};
        f32x4 acc1 = {0.f, 0.f, 0.f, 0.f};
#pragma unroll
        for (int ks = 0; ks < 4; ++ks) {
            acc0 = __builtin_amdgcn_mfma_f32_16x16x32_bf16(b[ks], a0[ks], acc0, 0, 0, 0);
            acc1 = __builtin_amdgcn_mfma_f32_16x16x32_bf16(b[ks], a1[ks], acc1, 0, 0, 0);
        }
        const int cb = nt * 16 + g4;
        if (cb < 128) {
            uint2 p0, p1;
            p0.x = pack2(acc0[0] * ns0, acc0[1] * ns0);
            p0.y = pack2(acc0[2] * ns0, acc0[3] * ns0);
            p1.x = pack2(acc1[0] * ns1, acc1[1] * ns1);
            p1.y = pack2(acc1[2] * ns1, acc1[3] * ns1);
            if (r0 < M) *reinterpret_cast<uint2*>(P + (size_t)r0 * 128 + cb) = p0;
            if (r1 < M) *reinterpret_cast<uint2*>(P + (size_t)r1 * 128 + cb) = p1;
        } else {
            const int oc = cb - 128;
            uint2 p0, p1;
            p0.x = pack2(acc0[0], acc0[1]); p0.y = pack2(acc0[2], acc0[3]);
            p1.x = pack2(acc1[0], acc1[1]); p1.y = pack2(acc1[2], acc1[3]);
            if (r0 < M) *reinterpret_cast<uint2*>(R + (size_t)r0 * 128 + oc) = p0;
            if (r1 < M) *reinterpret_cast<uint2*>(R + (size_t)r1 * 128 + oc) = p1;
        }
    }
}

// ---- final GEMM: out = [m2 | h2] @ Bt3^T + bias  (r6-validated) ------------
__global__ __launch_bounds__(256) void gemm_final(
    const short* __restrict__ M2,
    const short* __restrict__ H2,
    const short* __restrict__ Bt,      // 48 x 256
    const float* __restrict__ bias,
    float* __restrict__ OUT,
    int M)
{
    const int lane = threadIdx.x & 63;
    const int wid  = threadIdx.x >> 6;
    const int row0 = (blockIdx.x * 4 + wid) * 32;
    if (row0 >= M) return;
    const int lrow = lane & 15;
    const int lk8  = (lane >> 4) << 3;
    const int g4   = (lane >> 4) << 2;

    const int r0 = row0 + lrow, r1 = row0 + 16 + lrow;
    const int a0r = min(r0, M - 1), a1r = min(r1, M - 1);

    frag a0[8], a1[8];
#pragma unroll
    for (int ks = 0; ks < 4; ++ks) {
        a0[ks]     = *reinterpret_cast<const frag*>(M2 + (size_t)a0r * 128 + lk8 + ks * 32);
        a1[ks]     = *reinterpret_cast<const frag*>(M2 + (size_t)a1r * 128 + lk8 + ks * 32);
        a0[ks + 4] = *reinterpret_cast<const frag*>(H2 + (size_t)a0r * 128 + lk8 + ks * 32);
        a1[ks + 4] = *reinterpret_cast<const frag*>(H2 + (size_t)a1r * 128 + lk8 + ks * 32);
    }

#pragma unroll
    for (int nt = 0; nt < 3; ++nt) {
        frag b[8];
#pragma unroll
        for (int ks = 0; ks < 8; ++ks)
            b[ks] = *reinterpret_cast<const frag*>(Bt + (size_t)(nt * 16 + lrow) * 256 + lk8 + ks * 32);
        f32x4 acc0 = {0.f, 0.f, 0.f, 0.f};
        f32x4 acc1 = {0.f, 0.f, 0.f, 0.f};
#pragma unroll
        for (int ks = 0; ks < 8; ++ks) {
            acc0 = __builtin_amdgcn_mfma_f32_16x16x32_bf16(b[ks], a0[ks], acc0, 0, 0, 0);
            acc1 = __builtin_amdgcn_mfma_f32_16x16x32_bf16(b[ks], a1[ks], acc1, 0, 0, 0);
        }
        const int cb = nt * 16 + g4;
        if (cb + 3 < 40) {
            float4 bv = *reinterpret_cast<const float4*>(&bias[cb]);
            if (r0 < M) {
                float4 o = make_float4(acc0[0] + bv.x, acc0[1] + bv.y, acc0[2] + bv.z, acc0[3] + bv.w);
                *reinterpret_cast<float4*>(&OUT[(size_t)r0 * 40 + cb]) = o;
            }
            if (r1 < M) {
                float4 o = make_float4(acc1[0] + bv.x, acc1[1] + bv.y, acc1[2] + bv.z, acc1[3] + bv.w);
                *reinterpret_cast<float4*>(&OUT[(size_t)r1 * 40 + cb]) = o;
            }
        }
    }
}

// ---- aggregation: one wave per node, 4 edges per wave-load (r11-validated) -
// MODE 0: H += nd * sum P[s]           (bf16 in-place over residual)
// MODE 2: H  = nd * sum ns[s] * P[s]   (bf16 pure write)
template<int MODE>
__global__ __launch_bounds__(256) void agg_kernel(
    const uint4* __restrict__ P,       // N x 16 uint4 (= N x 128 bf16)
    const int* __restrict__ cnt_in,    // compact
    const int* __restrict__ slot,      // N x 64
    const float* __restrict__ norm_src,
    uint4* __restrict__ H,             // N x 16 uint4
    int N)
{
    const int node = blockIdx.x * 4 + (threadIdx.x >> 6);
    if (node >= N) return;
    const int lane = threadIdx.x & 63;
    const int sub  = lane >> 4;
    const int q    = lane & 15;

    const int cnt = cnt_in[node];
    const int c   = min(cnt, 64);
    const size_t sbase = (size_t)node << 6;
    const int cv = (lane < c) ? slot[sbase + lane] : 0;

    float a[8];
#pragma unroll
    for (int i = 0; i < 8; ++i) a[i] = 0.0f;

    int t = 0;
    for (; t + 4 <= c; t += 4) {
        int s = __shfl(cv, t + sub);
        uint4 u = P[(size_t)s * 16 + q];
        float f = (MODE == 2) ? norm_src[s] : 1.0f;
        a[0] += f * bflo(u.x); a[1] += f * bfhi(u.x);
        a[2] += f * bflo(u.y); a[3] += f * bfhi(u.y);
        a[4] += f * bflo(u.z); a[5] += f * bfhi(u.z);
        a[6] += f * bflo(u.w); a[7] += f * bfhi(u.w);
    }
    const int rem = c - t;
    if (rem > 0) {
        int s = __shfl(cv, t + (sub < rem ? sub : 0));   // all lanes execute
        if (sub < rem) {
            uint4 u = P[(size_t)s * 16 + q];
            float f = (MODE == 2) ? norm_src[s] : 1.0f;
            a[0] += f * bflo(u.x); a[1] += f * bfhi(u.x);
            a[2] += f * bflo(u.y); a[3] += f * bfhi(u.y);
            a[4] += f * bflo(u.z); a[5] += f * bfhi(u.z);
            a[6] += f * bflo(u.w); a[7] += f * bfhi(u.w);
        }
    }
#pragma unroll
    for (int i = 0; i < 8; ++i) {
        a[i] += __shfl_xor(a[i], 16);
        a[i] += __shfl_xor(a[i], 32);
    }
    if (sub == 0) {
        const float nd = rsqrtf((float)max(cnt, 1));
        const size_t o = (size_t)node * 16 + q;
        uint4 w;
        if (MODE == 2) {
            w.x = pack2(nd * a[0], nd * a[1]);
            w.y = pack2(nd * a[2], nd * a[3]);
            w.z = pack2(nd * a[4], nd * a[5]);
            w.w = pack2(nd * a[6], nd * a[7]);
        } else {
            uint4 r = H[o];
            w.x = pack2(bflo(r.x) + nd * a[0], bfhi(r.x) + nd * a[1]);
            w.y = pack2(bflo(r.y) + nd * a[2], bfhi(r.y) + nd * a[3]);
            w.z = pack2(bflo(r.z) + nd * a[4], bfhi(r.z) + nd * a[5]);
            w.w = pack2(bflo(r.w) + nd * a[6], bfhi(r.w) + nd * a[7]);
        }
        H[o] = w;
    }
}

// ---------------------------------------------------------------------------

extern "C" void kernel_launch(void* const* d_in, const int* in_sizes, int n_in,
                              void* d_out, int out_size, void* d_ws, size_t ws_size,
                              hipStream_t stream) {
    const float* feat = (const float*)d_in[0];
    const int*   src  = (const int*)d_in[1];
    const int*   dst  = (const int*)d_in[2];
    const float* W0   = (const float*)d_in[3];
    const float* W1   = (const float*)d_in[4];
    const float* W2   = (const float*)d_in[5];
    const float* b2   = (const float*)d_in[6];
    const float* L0   = (const float*)d_in[7];
    const float* L1   = (const float*)d_in[8];
    const float* L2   = (const float*)d_in[9];
    float* out = (float*)d_out;

    const int E = in_sizes[1];
    const int N = in_sizes[0] / 128;

    // ---- workspace layout ----
    float* fws      = (float*)d_ws;
    float* norm_src = fws;                        // N
    short* sws      = (short*)(fws + N);
    short* bufP     = sws;                        // N*128 (P scratch)
    short* bufA     = bufP + (size_t)N * 128;     // N*128 (R1 -> h1, later m2)
    short* bufB     = bufA + (size_t)N * 128;     // N*128 (h2)
    short* Bt1      = bufB + (size_t)N * 128;     // 256*128
    short* Bt2      = Bt1 + 256 * 128;
    short* Bt3      = Bt2 + 256 * 128;            // 48*256
    int*   iws      = (int*)(Bt3 + 48 * 256);
    int*   cnt_out  = iws;                        // N
    int*   cnt_in   = iws + N;                    // N (doubles as slot cursor)
    int*   slot     = iws + 2 * (size_t)N;        // N*64

    const int gblocks = (N + 127) / 128;
    const int ablocks = (N + 3) / 4;              // one node per wave

    // ---- graph build ----
    (void)hipMemsetAsync(cnt_out, 0, 2 * (size_t)N * sizeof(int), stream);
    build_kernel<<<(E + 255) / 256, 256, 0, stream>>>(src, dst, cnt_out, cnt_in, slot, E);
    norm_kernel<<<(N + 255) / 256, 256, 0, stream>>>(cnt_out, norm_src, N);

    pack128_kernel<<<(256 * 128 + 255) / 256, 256, 0, stream>>>(W0, L0, Bt1);
    pack128_kernel<<<(256 * 128 + 255) / 256, 256, 0, stream>>>(W1, L1, Bt2);
    pack_final_kernel<<<(48 * 256 + 255) / 256, 256, 0, stream>>>(W2, L2, Bt3);

    // layer 1: h1 = agg(P1) + R1                                   -> bufA
    gemm128<true><<<gblocks, 256, 0, stream>>>(feat, Bt1, norm_src, bufP, bufA, N);
    agg_kernel<0><<<ablocks, 256, 0, stream>>>((const uint4*)bufP, cnt_in, slot,
        nullptr, (uint4*)bufA, N);

    // layer 2: h2 = agg(P2) + R2                                   -> bufB
    gemm128<false><<<gblocks, 256, 0, stream>>>(bufA, Bt2, norm_src, bufP, bufB, N);
    agg_kernel<0><<<ablocks, 256, 0, stream>>>((const uint4*)bufP, cnt_in, slot,
        nullptr, (uint4*)bufB, N);

    // layer 3: m2 = nd * sum ns[s]*h2[s] -> bufA; out = [m2|h2]@Bt3 + b2
    agg_kernel<2><<<ablocks, 256, 0, stream>>>((const uint4*)bufB, cnt_in, slot,
        norm_src, (uint4*)bufA, N);
    gemm_final<<<gblocks, 256, 0, stream>>>(bufA, bufB, Bt3, b2, out, N);
}